// Round 3
// baseline (129.053 us; speedup 1.0000x reference)
//
#include <hip/hip_runtime.h>
#include <hip/hip_bf16.h>
#include <stdint.h>

#define N_W 96
#define N_F 96
#define NAG 192                      // total agents
#define NP1 97
#define W_ELEMS (N_W * NP1 * NP1)    // 903264 (divisible by 4)
#define R_ELEMS (NAG * NAG)          // 36864
#define WB ((W_ELEMS / 4 + 255) / 256)   // 883
#define RB ((R_ELEMS / 4 + 255) / 256)   // 36

// Decode one-hot tensors into packed index form.
// packed word [a*64 + s] = pref[a][s] | (pref[a][s+64] << 16)  (high half valid for s<33)
// ord[r] = dictating agent in round r (0..95 worker, 96..191 firm).
__global__ __launch_bounds__(256) void decode_kernel(
    const float* __restrict__ W, const float* __restrict__ F,
    const float* __restrict__ R,
    short* __restrict__ ps, short* __restrict__ ord) {
    int b = blockIdx.x;
    if (b < 2 * WB) {
        const float* src = (b < WB) ? W : F;
        int abase = (b < WB) ? 0 : N_W;
        int i4 = (b - ((b < WB) ? 0 : WB)) * 256 + threadIdx.x;
        if (i4 < W_ELEMS / 4) {
            float4 v = ((const float4*)src)[i4];
            int base = i4 * 4;
            #pragma unroll
            for (int u = 0; u < 4; ++u) {
                float x = (u == 0) ? v.x : (u == 1) ? v.y : (u == 2) ? v.z : v.w;
                if (x > 0.5f) {
                    int idx = base + u;
                    int a = idx / (NP1 * NP1);
                    int rem = idx - a * (NP1 * NP1);
                    int j = rem / NP1;          // option (firm/worker or 96=unmatch)
                    int k = rem - j * NP1;      // rank
                    int slot = (k < 64) ? (2 * k) : (2 * (k - 64) + 1);
                    ps[(abase + a) * 128 + slot] = (short)j;
                }
            }
        }
    } else {
        int i4 = (b - 2 * WB) * 256 + threadIdx.x;
        if (i4 < R_ELEMS / 4) {
            float4 v = ((const float4*)R)[i4];
            int base = i4 * 4;
            #pragma unroll
            for (int u = 0; u < 4; ++u) {
                float x = (u == 0) ? v.x : (u == 1) ? v.y : (u == 2) ? v.z : v.w;
                if (x > 0.5f) {
                    int idx = base + u;
                    int a = idx / NAG;
                    int r = idx - a * NAG;
                    ord[r] = (short)a;
                }
            }
        }
    }
}

// Single-block sequential serial dictatorship; scalarized round chain.
__global__ __launch_bounds__(256, 1) void sd_kernel(
    const uint32_t* __restrict__ pk_g, const short* __restrict__ ord_g,
    float* __restrict__ out) {
    __shared__ __align__(16) uint32_t s_pk[NAG * 64];   // 48 KiB packed prefs
    __shared__ short s_ord[NAG];
    __shared__ uint32_t s_match[NAG];                   // matched cell per round, ~0 = none

    const int t = threadIdx.x;
    for (int i = t; i < NAG * 16; i += 256)
        ((uint4*)s_pk)[i] = ((const uint4*)pk_g)[i];
    if (t < NAG) { s_ord[t] = ord_g[t]; s_match[t] = 0xFFFFFFFFu; }
    __syncthreads();

    if (t < 64) {
        // removal (rem) and annihilation (zero) masks, 96 bits each as 3xu32 (uniform -> SGPR)
        uint32_t rW0 = 0, rW1 = 0, rW2 = 0, rF0 = 0, rF1 = 0, rF2 = 0;
        uint32_t zW0 = 0, zW1 = 0, zW2 = 0, zF0 = 0, zF1 = 0, zF2 = 0;
        const uint32_t lane_ok2 = (t < 33) ? 0xFFFFFFFFu : 0u;  // slot2 valid only for ranks 64..96

        int agA[8]; uint32_t ppA[8]; uint32_t BA[8][6];
        int agB[8]; uint32_t ppB[8]; uint32_t BB[8][6];

        auto LOADG = [&](int g, int* ag_, uint32_t* pp_) {
            int ov = (int)s_ord[(g << 3) + (t & 7)];
            #pragma unroll
            for (int i = 0; i < 8; ++i) ag_[i] = __builtin_amdgcn_readlane(ov, i);
            #pragma unroll
            for (int i = 0; i < 8; ++i) pp_[i] = s_pk[(ag_[i] << 6) + t];
        };
        auto PRECB = [&](const uint32_t* pp_, uint32_t (*B_)[6]) {
            #pragma unroll
            for (int i = 0; i < 8; ++i) {
                uint32_t p = pp_[i];
                int j1 = (int)(p & 0xFFFFu), j2 = (int)(p >> 16);
                uint32_t b1 = (j1 < 96) ? (1u << (j1 & 31)) : 0u;
                uint32_t b2 = ((j2 < 96) ? (1u << (j2 & 31)) : 0u) & lane_ok2;
                int w1 = j1 >> 5, w2 = j2 >> 5;
                B_[i][0] = (w1 == 0) ? b1 : 0u;
                B_[i][1] = (w1 == 1) ? b1 : 0u;
                B_[i][2] = (w1 == 2) ? b1 : 0u;
                B_[i][3] = (w2 == 0) ? b2 : 0u;
                B_[i][4] = (w2 == 1) ? b2 : 0u;
                B_[i][5] = (w2 == 2) ? b2 : 0u;
            }
        };

        auto ROUND = [&](int r, int a, uint32_t p, const uint32_t* B) {
            if (a < N_W) {               // worker dictates (uniform branch)
                int aa = a;
                uint32_t sb = 1u << (aa & 31);
                int swi = aa >> 5;
                uint32_t zsel = (swi == 0) ? zW0 : (swi == 1) ? zW1 : zW2;
                rW0 |= (swi == 0) ? sb : 0u;        // self-removal from firms' lists
                rW1 |= (swi == 1) ? sb : 0u;
                rW2 |= (swi == 2) ? sb : 0u;
                if (((zsel >> (aa & 31)) & 1u) == 0u) {   // alive?
                    bool av1 = ((rF0 & B[0]) | (rF1 & B[1]) | (rF2 & B[2])) == 0u;
                    bool av2 = ((rF0 & B[3]) | (rF1 & B[4]) | (rF2 & B[5])) == 0u;
                    unsigned long long m1 = __ballot(av1);
                    unsigned long long m2 = __ballot(av2);
                    int k = (m1 != 0ull) ? (__ffsll(m1) - 1) : (63 + __ffsll(m2));
                    uint32_t pc = (uint32_t)__builtin_amdgcn_readlane((int)p, k & 63);
                    int js = (k < 64) ? (int)(pc & 0xFFFFu) : (int)(pc >> 16);
                    s_match[r] = (uint32_t)(aa * NP1 + js);
                    if (js < 96) {                  // real firm chosen: remove + annihilate
                        uint32_t cb = 1u << (js & 31);
                        int cwi = js >> 5;
                        uint32_t c0 = (cwi == 0) ? cb : 0u;
                        uint32_t c1 = (cwi == 1) ? cb : 0u;
                        uint32_t c2 = (cwi == 2) ? cb : 0u;
                        rF0 |= c0; rF1 |= c1; rF2 |= c2;
                        zF0 |= c0; zF1 |= c1; zF2 |= c2;
                    }
                }
            } else {                      // firm dictates (mirror)
                int aa = a - N_W;
                uint32_t sb = 1u << (aa & 31);
                int swi = aa >> 5;
                uint32_t zsel = (swi == 0) ? zF0 : (swi == 1) ? zF1 : zF2;
                rF0 |= (swi == 0) ? sb : 0u;
                rF1 |= (swi == 1) ? sb : 0u;
                rF2 |= (swi == 2) ? sb : 0u;
                if (((zsel >> (aa & 31)) & 1u) == 0u) {
                    bool av1 = ((rW0 & B[0]) | (rW1 & B[1]) | (rW2 & B[2])) == 0u;
                    bool av2 = ((rW0 & B[3]) | (rW1 & B[4]) | (rW2 & B[5])) == 0u;
                    unsigned long long m1 = __ballot(av1);
                    unsigned long long m2 = __ballot(av2);
                    int k = (m1 != 0ull) ? (__ffsll(m1) - 1) : (63 + __ffsll(m2));
                    uint32_t pc = (uint32_t)__builtin_amdgcn_readlane((int)p, k & 63);
                    int js = (k < 64) ? (int)(pc & 0xFFFFu) : (int)(pc >> 16);
                    s_match[r] = (uint32_t)(js * NP1 + aa);
                    if (js < 96) {
                        uint32_t cb = 1u << (js & 31);
                        int cwi = js >> 5;
                        uint32_t c0 = (cwi == 0) ? cb : 0u;
                        uint32_t c1 = (cwi == 1) ? cb : 0u;
                        uint32_t c2 = (cwi == 2) ? cb : 0u;
                        rW0 |= c0; rW1 |= c1; rW2 |= c2;
                        zW0 |= c0; zW1 |= c1; zW2 |= c2;
                    }
                }
            }
        };

        LOADG(0, agA, ppA); PRECB(ppA, BA);
        for (int g = 0; g < 24; g += 2) {
            LOADG(g + 1, agB, ppB); PRECB(ppB, BB);      // prefetch next group (off-chain)
            #pragma unroll
            for (int i = 0; i < 8; ++i) ROUND((g << 3) + i, agA[i], ppA[i], BA[i]);
            if (g + 2 < 24) { LOADG(g + 2, agA, ppA); PRECB(ppA, BA); }
            #pragma unroll
            for (int i = 0; i < 8; ++i) ROUND(((g + 1) << 3) + i, agB[i], ppB[i], BB[i]);
        }
    } else {
        // waves 1-3: zero-fill output concurrently with wave 0's sequential loop
        for (int i = t - 64; i < 2352; i += 192)
            ((float4*)out)[i] = make_float4(0.f, 0.f, 0.f, 0.f);
        if (t == 64) out[9408] = 0.f;
    }
    __syncthreads();
    if (t < NAG) {
        uint32_t c = s_match[t];
        if (c != 0xFFFFFFFFu) out[c] = 1.0f;
    }
}

extern "C" void kernel_launch(void* const* d_in, const int* in_sizes, int n_in,
                              void* d_out, int out_size, void* d_ws, size_t ws_size,
                              hipStream_t stream) {
    const float* W = (const float*)d_in[0];
    const float* F = (const float*)d_in[1];
    const float* R = (const float*)d_in[2];
    float* out = (float*)d_out;

    uint32_t* packed = (uint32_t*)d_ws;                 // NAG*64 u32 = 48 KiB
    short* ord = (short*)((char*)d_ws + NAG * 64 * 4);  // 192 shorts

    decode_kernel<<<2 * WB + RB, 256, 0, stream>>>(W, F, R, (short*)packed, ord);
    sd_kernel<<<1, 256, 0, stream>>>(packed, ord, out);
}

// Round 4
// 59.715 us; speedup vs baseline: 2.1612x; 2.1612x over previous
//
#include <hip/hip_runtime.h>
#include <hip/hip_bf16.h>
#include <stdint.h>

#define N_W 96
#define N_F 96
#define NAG 192                      // total agents
#define NP1 97
#define W_ELEMS (N_W * NP1 * NP1)    // 903264 (divisible by 4)
#define R_ELEMS (NAG * NAG)          // 36864
#define WB ((W_ELEMS / 4 + 255) / 256)   // 883
#define RB ((R_ELEMS / 4 + 255) / 256)   // 36

// Decode one-hot tensors into packed index form.
// packed word [a*64 + s] = pref[a][s] | (pref[a][s+64] << 16)  (high half valid for s<33)
// ord[r] = dictating agent in round r (0..95 worker, 96..191 firm).
__global__ __launch_bounds__(256) void decode_kernel(
    const float* __restrict__ W, const float* __restrict__ F,
    const float* __restrict__ R,
    short* __restrict__ ps, short* __restrict__ ord) {
    int b = blockIdx.x;
    if (b < 2 * WB) {
        const float* src = (b < WB) ? W : F;
        int abase = (b < WB) ? 0 : N_W;
        int i4 = (b - ((b < WB) ? 0 : WB)) * 256 + threadIdx.x;
        if (i4 < W_ELEMS / 4) {
            float4 v = ((const float4*)src)[i4];
            int base = i4 * 4;
            #pragma unroll
            for (int u = 0; u < 4; ++u) {
                float x = (u == 0) ? v.x : (u == 1) ? v.y : (u == 2) ? v.z : v.w;
                if (x > 0.5f) {
                    int idx = base + u;
                    int a = idx / (NP1 * NP1);
                    int rem = idx - a * (NP1 * NP1);
                    int j = rem / NP1;          // option (firm/worker or 96=unmatch)
                    int k = rem - j * NP1;      // rank
                    int slot = (k < 64) ? (2 * k) : (2 * (k - 64) + 1);
                    ps[(abase + a) * 128 + slot] = (short)j;
                }
            }
        }
    } else {
        int i4 = (b - 2 * WB) * 256 + threadIdx.x;
        if (i4 < R_ELEMS / 4) {
            float4 v = ((const float4*)R)[i4];
            int base = i4 * 4;
            #pragma unroll
            for (int u = 0; u < 4; ++u) {
                float x = (u == 0) ? v.x : (u == 1) ? v.y : (u == 2) ? v.z : v.w;
                if (x > 0.5f) {
                    int idx = base + u;
                    int a = idx / NAG;
                    int r = idx - a * NAG;
                    ord[r] = (short)a;
                }
            }
        }
    }
}

// Single-block sequential serial dictatorship.
// Masks live in wave-uniform u64 locals (SGPR-resident); per-round critical
// chain is shift/and_or/ballot/ffs/readlane only. Prefs prefetched 1 round
// ahead, dictator ids 2 rounds ahead; no register arrays.
__global__ __launch_bounds__(256, 1) void sd_kernel(
    const uint32_t* __restrict__ pk_g, const short* __restrict__ ord_g,
    float* __restrict__ out) {
    __shared__ __align__(16) uint32_t s_pk[NAG * 64];   // 48 KiB packed prefs
    __shared__ short s_ord[NAG + 8];                    // padded for prefetch overrun
    __shared__ uint32_t s_match[NAG];                   // matched cell per round, ~0 = none

    const int t = threadIdx.x;
    for (int i = t; i < NAG * 16; i += 256)
        ((uint4*)s_pk)[i] = ((const uint4*)pk_g)[i];
    if (t < NAG) { s_ord[t] = ord_g[t]; s_match[t] = 0xFFFFFFFFu; }
    if (t >= NAG && t < NAG + 8) s_ord[t] = 0;
    __syncthreads();

    if (t < 64) {
        // removal (r*) and annihilation (z*) masks; lo = agents 0..63, hi = 64..96.
        // Updated only from uniform scalars -> SGPR-resident.
        uint64_t rWlo = 0, rWhi = 0, rFlo = 0, rFhi = 0;
        uint64_t zWlo = 0, zWhi = 0, zFlo = 0, zFhi = 0;
        const uint32_t inv2 = (t < 33) ? 0u : 1u;   // hi slot valid only for lanes 0..32

        // prologue: rounds 0,1 dictators + prefs; round-2 ord read in flight
        int a_cur = __builtin_amdgcn_readfirstlane((int)s_ord[0]);
        int a_nx  = __builtin_amdgcn_readfirstlane((int)s_ord[1]);
        int ov_fut = (int)s_ord[2];
        uint32_t p_cur = s_pk[(a_cur << 6) + t];
        uint32_t p_nx  = s_pk[(a_nx << 6) + t];
        int j1 = (int)(p_cur & 0xFFFFu), j2 = (int)(p_cur >> 16);
        uint32_t sl1 = (j1 < 64) ? 1u : 0u, sh1 = (j1 >= 64 && j1 < 96) ? 1u : 0u;
        uint32_t sl2 = (j2 < 64) ? 1u : 0u, sh2 = (j2 >= 64 && j2 < 96) ? 1u : 0u;

        #pragma unroll 3
        for (int r = 0; r < NAG; ++r) {
            // prefetch: ord two ahead, prefs one ahead (off the serial chain)
            int ov_new = (int)s_ord[r + 3];
            int a_fut = __builtin_amdgcn_readfirstlane(ov_fut);
            uint32_t p_fut = s_pk[(a_fut << 6) + t];

            // ---- round r (uniform scalar branches) ----
            bool isW = a_cur < N_W;
            int aa = isW ? a_cur : a_cur - N_W;
            uint64_t sb_lo = (aa < 64) ? (1ull << aa) : 0ull;
            uint64_t sb_hi = (aa < 64) ? 0ull : (1ull << (aa - 64));
            if (isW) {
                rWlo |= sb_lo; rWhi |= sb_hi;               // self-removal from firms' lists
                if ((((aa < 64) ? (zWlo >> aa) : (zWhi >> (aa - 64))) & 1ull) == 0ull) {
                    uint32_t bad1 = (((uint32_t)(rFlo >> (j1 & 63))) & sl1)
                                  | (((uint32_t)(rFhi >> (j1 & 63))) & sh1);
                    uint32_t bad2 = (((uint32_t)(rFlo >> (j2 & 63))) & sl2)
                                  | (((uint32_t)(rFhi >> (j2 & 63))) & sh2) | inv2;
                    unsigned long long m1 = __ballot(bad1 == 0u);
                    unsigned long long m2 = __ballot(bad2 == 0u);
                    int k = (m1 != 0ull) ? (__ffsll(m1) - 1) : (63 + __ffsll(m2));
                    uint32_t pc = (uint32_t)__builtin_amdgcn_readlane((int)p_cur, k & 63);
                    int js = (k < 64) ? (int)(pc & 0xFFFFu) : (int)(pc >> 16);
                    js = __builtin_amdgcn_readfirstlane(js);
                    if (t == 0) s_match[r] = (uint32_t)(aa * NP1 + js);
                    if (js < 96) {
                        uint64_t cb_lo = (js < 64) ? (1ull << js) : 0ull;
                        uint64_t cb_hi = (js < 64) ? 0ull : (1ull << (js - 64));
                        rFlo |= cb_lo; rFhi |= cb_hi;       // remove chosen firm
                        zFlo |= cb_lo; zFhi |= cb_hi;       // annihilate chosen firm
                    }
                }
            } else {
                rFlo |= sb_lo; rFhi |= sb_hi;
                if ((((aa < 64) ? (zFlo >> aa) : (zFhi >> (aa - 64))) & 1ull) == 0ull) {
                    uint32_t bad1 = (((uint32_t)(rWlo >> (j1 & 63))) & sl1)
                                  | (((uint32_t)(rWhi >> (j1 & 63))) & sh1);
                    uint32_t bad2 = (((uint32_t)(rWlo >> (j2 & 63))) & sl2)
                                  | (((uint32_t)(rWhi >> (j2 & 63))) & sh2) | inv2;
                    unsigned long long m1 = __ballot(bad1 == 0u);
                    unsigned long long m2 = __ballot(bad2 == 0u);
                    int k = (m1 != 0ull) ? (__ffsll(m1) - 1) : (63 + __ffsll(m2));
                    uint32_t pc = (uint32_t)__builtin_amdgcn_readlane((int)p_cur, k & 63);
                    int js = (k < 64) ? (int)(pc & 0xFFFFu) : (int)(pc >> 16);
                    js = __builtin_amdgcn_readfirstlane(js);
                    if (t == 0) s_match[r] = (uint32_t)(js * NP1 + aa);
                    if (js < 96) {
                        uint64_t cb_lo = (js < 64) ? (1ull << js) : 0ull;
                        uint64_t cb_hi = (js < 64) ? 0ull : (1ull << (js - 64));
                        rWlo |= cb_lo; rWhi |= cb_hi;
                        zWlo |= cb_lo; zWhi |= cb_hi;
                    }
                }
            }

            // derive next round's per-lane test words (independent of the chain)
            int j1n = (int)(p_nx & 0xFFFFu), j2n = (int)(p_nx >> 16);
            uint32_t sl1n = (j1n < 64) ? 1u : 0u, sh1n = (j1n >= 64 && j1n < 96) ? 1u : 0u;
            uint32_t sl2n = (j2n < 64) ? 1u : 0u, sh2n = (j2n >= 64 && j2n < 96) ? 1u : 0u;

            // rotate pipeline (plain scalars; unroll-3 renames these away)
            a_cur = a_nx; a_nx = a_fut;
            p_cur = p_nx; p_nx = p_fut;
            ov_fut = ov_new;
            j1 = j1n; j2 = j2n; sl1 = sl1n; sh1 = sh1n; sl2 = sl2n; sh2 = sh2n;
        }
    } else {
        // waves 1-3: zero-fill output concurrently with wave 0's sequential loop
        for (int i = t - 64; i < 2352; i += 192)
            ((float4*)out)[i] = make_float4(0.f, 0.f, 0.f, 0.f);
        if (t == 64) out[9408] = 0.f;
    }
    __syncthreads();
    if (t < NAG) {
        uint32_t c = s_match[t];
        if (c != 0xFFFFFFFFu) out[c] = 1.0f;
    }
}

extern "C" void kernel_launch(void* const* d_in, const int* in_sizes, int n_in,
                              void* d_out, int out_size, void* d_ws, size_t ws_size,
                              hipStream_t stream) {
    const float* W = (const float*)d_in[0];
    const float* F = (const float*)d_in[1];
    const float* R = (const float*)d_in[2];
    float* out = (float*)d_out;

    uint32_t* packed = (uint32_t*)d_ws;                 // NAG*64 u32 = 48 KiB
    short* ord = (short*)((char*)d_ws + NAG * 64 * 4);  // 192 shorts

    decode_kernel<<<2 * WB + RB, 256, 0, stream>>>(W, F, R, (short*)packed, ord);
    sd_kernel<<<1, 256, 0, stream>>>(packed, ord, out);
}